// Round 5
// baseline (212.706 us; speedup 1.0000x reference)
//
#include <hip/hip_runtime.h>
#include <math.h>

// Problem constants
#define BB 16      // batch
#define LL 32      // L
#define AA 2046    // attributor cols
#define MM 2048    // M = A + 2
#define NROWS 192  // 6L

// Workspace layout (floats, after a 32-int counter block):
//   cnt  [32] ints      (cnt[b]: stc blocks done; cnt[16+b]: gather blocks done)
//   part [4][2][16][2048]  rc-chunk partials of s/t over interior cols (col idx)
//   bnd  [4][2][16][2]     boundary-column (n=0 user / n=M-1 item) partials
//   c    [2][16][2048]     causal weights for target cols {0, M-1}
//   gg   [16][64][2]       per-value-row reduced sums g_j[b,r]

// ---------------------------------------------------------------------------
// Kernel 1: fused prep + s/t partials + (last block per b) causal weights.
//   rc 0,1: s-partials over r in [rc*32, rc*32+32) with weights u0/u1 (z=0)
//   rc 2,3: t-partials, weights v0/v1 (z=1, w-index r-64)
//   u_j[r] = W2[r,:]·K_j,  K_j[l] = sum_{r'=64..127} relu(src_j[b,r'])·W2[r',l]
//   v_j[r] = W2[64+r,:]·Q_j, Q_j from rows 0..63.   (src_0=user, src_1=item)
// Prep is recomputed per block from L2-resident user/item/W2 (~4k FMA).
// Last of the 16 blocks per b (device-scope counter + threadfence) computes
//   d_j(n) = s_j·adj[n,mj]·iw[n,mj] − t_j·adj[mj,n]·iw[mj,n]
//   c_j(n) = sigmoid(d_j)·adj[n,mj]          (== stable exp(min(d,0)) form)
// grid (4 coltiles, 16 b, 4 rc) = 256 blocks x 256 thr; float2 everywhere.
// ---------------------------------------------------------------------------
__global__ __launch_bounds__(256) void stc_kernel(
    const float* __restrict__ user, const float* __restrict__ item,
    const float* __restrict__ att, const float* __restrict__ W1,
    const float* __restrict__ W2, const float* __restrict__ adj,
    const float* __restrict__ iw, int* __restrict__ cnt,
    float* __restrict__ part, float* __restrict__ bnd, float* __restrict__ c) {
  const int x = blockIdx.x, b = blockIdx.y, rc = blockIdx.z;
  const int t = threadIdx.x;
  const int z = rc >> 1;
  __shared__ float KQ[2][LL];
  __shared__ float uvs[2][64];
  __shared__ int lastflag;

  // --- embedded prep ---
  if (t < 64) {
    const int j = t >> 5, l = t & 31;
    const float* __restrict__ src = j ? item : user;
    const int rbase = (z == 0) ? 64 : 0;  // K from rows 64..127, Q from 0..63
    float acc = 0.f;
#pragma unroll
    for (int r = 0; r < 64; ++r)
      acc += fmaxf(src[b * NROWS + rbase + r], 0.f) * W2[(rbase + r) * LL + l];
    KQ[j][l] = acc;
  }
  __syncthreads();
  if (t < 128) {
    const int j = t >> 6, r = t & 63;
    const int wrow = (z == 0) ? r : 64 + r;
    float acc = 0.f;
#pragma unroll
    for (int l = 0; l < LL; ++l) acc += W2[wrow * LL + l] * KQ[j][l];
    uvs[j][r] = acc;
  }
  __syncthreads();

  // --- main: 2 interior cols per thread, float2 loads (8B-aligned) ---
  const int col0 = x * 512 + 2 * t;
  const int r0 = rc * 32;
  const int wibase = r0 - z * 64;
  if (col0 < AA) {
    float a00 = 0.f, a01 = 0.f, a10 = 0.f, a11 = 0.f;
#pragma unroll
    for (int i = 0; i < 32; ++i) {
      const int r = r0 + i;
      const float2 av =
          ((const float2*)att)[((size_t)(b * NROWS + r) * AA + col0) >> 1];
      const float2 wv = ((const float2*)W1)[((size_t)r * AA + col0) >> 1];
      const float v0 = fmaxf(av.x * wv.x, 0.f);
      const float v1 = fmaxf(av.y * wv.y, 0.f);
      const float u0 = uvs[0][wibase + i], u1 = uvs[1][wibase + i];
      a00 += v0 * u0;
      a01 += v1 * u0;
      a10 += v0 * u1;
      a11 += v1 * u1;
    }
    float* p0 = part + ((size_t)(rc * 2 + 0) * BB + b) * 2048;
    float* p1 = part + ((size_t)(rc * 2 + 1) * BB + b) * 2048;
    ((float2*)p0)[col0 >> 1] = make_float2(a00, a01);
    ((float2*)p1)[col0 >> 1] = make_float2(a10, a11);
  }

  // --- boundary columns n=0 (user) / n=M-1 (item), done once (x==0) ---
  if (x == 0 && t >= 128 && t < 132) {
    const int idx = t - 128, which = idx & 1, j = idx >> 1;
    const float* __restrict__ src = which ? item : user;
    float acc = 0.f;
#pragma unroll
    for (int i = 0; i < 32; ++i)
      acc += fmaxf(src[b * NROWS + r0 + i], 0.f) * uvs[j][wibase + i];
    bnd[((rc * 2 + j) * BB + b) * 2 + which] = acc;
  }

  // --- last-block-per-b epilogue: causal weights ---
  __threadfence();  // release this block's stores (device scope)
  __syncthreads();
  if (t == 0) {
    const int old = atomicAdd(&cnt[b], 1);
    lastflag = (old == 16 - 1);  // 4 x-tiles * 4 rc per b
  }
  __syncthreads();
  if (!lastflag) return;
  __threadfence();  // acquire other blocks' stores

#pragma unroll
  for (int i = 0; i < 8; ++i) {
    const int n = i * 256 + t;
    float s0, s1, t0v, t1v;
    if (n == 0 || n == MM - 1) {
      const int which = (n == 0) ? 0 : 1;
      s0 = bnd[(0 * BB + b) * 2 + which] + bnd[(2 * BB + b) * 2 + which];
      s1 = bnd[(1 * BB + b) * 2 + which] + bnd[(3 * BB + b) * 2 + which];
      t0v = bnd[(4 * BB + b) * 2 + which] + bnd[(6 * BB + b) * 2 + which];
      t1v = bnd[(5 * BB + b) * 2 + which] + bnd[(7 * BB + b) * 2 + which];
    } else {
      const int col = n - 1;
      s0 = part[((size_t)0 * BB + b) * 2048 + col] +
           part[((size_t)2 * BB + b) * 2048 + col];
      s1 = part[((size_t)1 * BB + b) * 2048 + col] +
           part[((size_t)3 * BB + b) * 2048 + col];
      t0v = part[((size_t)4 * BB + b) * 2048 + col] +
            part[((size_t)6 * BB + b) * 2048 + col];
      t1v = part[((size_t)5 * BB + b) * 2048 + col] +
            part[((size_t)7 * BB + b) * 2048 + col];
    }
    const float an0 = adj[(size_t)n * MM];
    const float an1 = adj[(size_t)n * MM + (MM - 1)];
    const float wn0 = an0 * iw[(size_t)n * MM];
    const float wn1 = an1 * iw[(size_t)n * MM + (MM - 1)];
    const float w0n = adj[n] * iw[n];
    const float w1n =
        adj[(size_t)(MM - 1) * MM + n] * iw[(size_t)(MM - 1) * MM + n];
    const float d0 = s0 * wn0 - t0v * w0n;
    const float d1 = s1 * wn1 - t1v * w1n;
    const float e0 = expf(-fabsf(d0));
    const float e1 = expf(-fabsf(d1));
    const float sig0 = (d0 > 0.f) ? 1.f / (1.f + e0) : e0 / (1.f + e0);
    const float sig1 = (d1 > 0.f) ? 1.f / (1.f + e1) : e1 / (1.f + e1);
    c[b * MM + n] = sig0 * an0;
    c[BB * MM + b * MM + n] = sig1 * an1;
  }
}

// ---------------------------------------------------------------------------
// Kernel 2: g_j[b,r] = sum_n relu(raw[b,128+rv,n])·c_j[b,n]  (wave-shuffle
// reduce, float2 loads), then last block per b does the final projection
//   out[b,l,j] = sum_rv W2[128+rv,l]·g_j[b,rv]   (plain stores, no memset).
// grid (64 rv, 16 b) = 1024 blocks x 256 thr.
// ---------------------------------------------------------------------------
__global__ __launch_bounds__(256) void gather_kernel(
    const float* __restrict__ user, const float* __restrict__ item,
    const float* __restrict__ att, const float* __restrict__ W1,
    const float* __restrict__ W2, const float* __restrict__ c,
    int* __restrict__ cnt, float* __restrict__ gg, float* __restrict__ out) {
  const int rv = blockIdx.x, b = blockIdx.y, t = threadIdx.x;
  const int r = 128 + rv;
  const int gr = b * NROWS + r;
  const float* __restrict__ c0 = c + b * MM;
  const float* __restrict__ c1 = c + BB * MM + b * MM;
  float g0 = 0.f, g1 = 0.f;
#pragma unroll
  for (int i = 0; i < 4; ++i) {
    const int col = i * 512 + 2 * t;
    if (col < AA) {
      const float2 av = ((const float2*)att)[((size_t)gr * AA + col) >> 1];
      const float2 wv = ((const float2*)W1)[((size_t)r * AA + col) >> 1];
      const float v0 = fmaxf(av.x * wv.x, 0.f);
      const float v1 = fmaxf(av.y * wv.y, 0.f);
      g0 += v0 * c0[col + 1] + v1 * c0[col + 2];
      g1 += v0 * c1[col + 1] + v1 * c1[col + 2];
    }
  }
  if (t == 0) {  // boundary cols n=0 (user) / n=M-1 (item)
    const float uval = fmaxf(user[gr], 0.f);
    const float ival = fmaxf(item[gr], 0.f);
    g0 += uval * c0[0] + ival * c0[MM - 1];
    g1 += uval * c1[0] + ival * c1[MM - 1];
  }
#pragma unroll
  for (int o = 32; o > 0; o >>= 1) {
    g0 += __shfl_down(g0, o);
    g1 += __shfl_down(g1, o);
  }
  __shared__ float rg[2][4];
  __shared__ int lastflag;
  if ((t & 63) == 0) {
    rg[0][t >> 6] = g0;
    rg[1][t >> 6] = g1;
  }
  __syncthreads();
  if (t == 0) {
    const float s0 = rg[0][0] + rg[0][1] + rg[0][2] + rg[0][3];
    const float s1 = rg[1][0] + rg[1][1] + rg[1][2] + rg[1][3];
    ((float2*)gg)[b * 64 + rv] = make_float2(s0, s1);
  }
  __threadfence();  // release gg store
  __syncthreads();
  if (t == 0) {
    const int old = atomicAdd(&cnt[16 + b], 1);
    lastflag = (old == 64 - 1);
  }
  __syncthreads();
  if (!lastflag) return;
  __threadfence();  // acquire other blocks' gg

  if (t < 64) {
    const int l = t & 31, j = t >> 5;
    float acc = 0.f;
#pragma unroll
    for (int i = 0; i < 64; ++i)
      acc += W2[(128 + i) * LL + l] * gg[(b * 64 + i) * 2 + j];
    out[b * 64 + l * 2 + j] = acc;
  }
}

extern "C" void kernel_launch(void* const* d_in, const int* in_sizes, int n_in,
                              void* d_out, int out_size, void* d_ws,
                              size_t ws_size, hipStream_t stream) {
  const float* user = (const float*)d_in[0];
  const float* item = (const float*)d_in[1];
  const float* att = (const float*)d_in[2];
  const float* adj = (const float*)d_in[3];
  const float* iw = (const float*)d_in[4];
  const float* W1 = (const float*)d_in[5];
  const float* W2 = (const float*)d_in[6];
  float* out = (float*)d_out;

  int* cnt = (int*)d_ws;                  // 32 ints (128 B)
  float* part = (float*)d_ws + 32;        // 4*2*16*2048 = 262144 floats
  float* bnd = part + 262144;             // 4*2*16*2 = 256 floats
  float* c = bnd + 256;                   // 2*16*2048 = 65536 floats
  float* gg = c + 65536;                  // 16*64*2 = 2048 floats

  hipMemsetAsync(cnt, 0, 32 * sizeof(int), stream);

  stc_kernel<<<dim3(4, BB, 4), 256, 0, stream>>>(user, item, att, W1, W2, adj,
                                                 iw, cnt, part, bnd, c);
  gather_kernel<<<dim3(64, BB), 256, 0, stream>>>(user, item, att, W1, W2, c,
                                                  cnt, gg, out);
}

// Round 6
// 116.426 us; speedup vs baseline: 1.8270x; 1.8270x over previous
//
#include <hip/hip_runtime.h>
#include <math.h>

// Problem constants
#define BB 16      // batch
#define LL 32      // L
#define AA 2046    // attributor cols
#define MM 2048    // M = A + 2
#define NROWS 192  // 6L

// Workspace layout (floats):
//   part[4][2][16][2048]  rc-chunk partials of s/t over interior cols (col idx)
//   bnd [4][2][16][2]     boundary-column (n=0 user / n=M-1 item) partials
//   c   [2][16][2048]     causal weights for target cols {0, M-1}
//   gg  [16][64][2]       per-value-row reduced sums g_j[b,r]
//
// NOTE (R5 post-mortem): NO device-scope fences / last-block patterns —
// __threadfence() on gfx950 costs an L2 writeback per call (per-XCD L2s are
// non-coherent); 1024 blocks × fence serialized into 76 µs. Kernel boundaries
// are the cheap coherence mechanism here.

// ---------------------------------------------------------------------------
// Kernel 1: embedded prep + s/t partial dot-products, branch-free, float2.
//   rc 0,1 (z=0): s-partials over r in [rc*32, rc*32+32), weights u0/u1
//   rc 2,3 (z=1): t-partials, weights v0/v1 (w-index r-64)
//   u_j[r] = W2[r,:]·K_j,   K_j[l] = sum_{r'=64..127} relu(src_j[b,r'])·W2[r',l]
//   v_j[r] = W2[64+r,:]·Q_j, Q_j from rows 0..63.  (src_0=user, src_1=item)
// Boundary cols n=0 (user) / n=M-1 (item) done by x==0 blocks into bnd[].
// grid (4 coltiles, 16 b, 4 rc) = 256 blocks x 256 thr.
// ---------------------------------------------------------------------------
__global__ __launch_bounds__(256) void stc_kernel(
    const float* __restrict__ user, const float* __restrict__ item,
    const float* __restrict__ att, const float* __restrict__ W1,
    const float* __restrict__ W2, float* __restrict__ part,
    float* __restrict__ bnd) {
  const int x = blockIdx.x, b = blockIdx.y, rc = blockIdx.z;
  const int t = threadIdx.x;
  const int z = rc >> 1;
  __shared__ float KQ[2][LL];
  __shared__ float uvs[2][64];

  // --- embedded prep (L2-hot inputs, ~4k FMA) ---
  if (t < 64) {
    const int j = t >> 5, l = t & 31;
    const float* __restrict__ src = j ? item : user;
    const int rbase = (z == 0) ? 64 : 0;  // K from rows 64..127, Q from 0..63
    float acc = 0.f;
#pragma unroll
    for (int r = 0; r < 64; ++r)
      acc += fmaxf(src[b * NROWS + rbase + r], 0.f) * W2[(rbase + r) * LL + l];
    KQ[j][l] = acc;
  }
  __syncthreads();
  if (t < 128) {
    const int j = t >> 6, r = t & 63;
    const int wrow = (z == 0) ? r : 64 + r;
    float acc = 0.f;
#pragma unroll
    for (int l = 0; l < LL; ++l) acc += W2[wrow * LL + l] * KQ[j][l];
    uvs[j][r] = acc;
  }
  __syncthreads();

  // --- main: 2 interior cols per thread, float2 loads (8B-aligned) ---
  const int col0 = x * 512 + 2 * t;
  const int r0 = rc * 32;
  const int wibase = r0 - z * 64;
  if (col0 < AA) {
    float a00 = 0.f, a01 = 0.f, a10 = 0.f, a11 = 0.f;
#pragma unroll
    for (int i = 0; i < 32; ++i) {
      const int r = r0 + i;
      const float2 av =
          ((const float2*)att)[((size_t)(b * NROWS + r) * AA + col0) >> 1];
      const float2 wv = ((const float2*)W1)[((size_t)r * AA + col0) >> 1];
      const float v0 = fmaxf(av.x * wv.x, 0.f);
      const float v1 = fmaxf(av.y * wv.y, 0.f);
      const float u0 = uvs[0][wibase + i], u1 = uvs[1][wibase + i];
      a00 += v0 * u0;
      a01 += v1 * u0;
      a10 += v0 * u1;
      a11 += v1 * u1;
    }
    float* p0 = part + ((size_t)(rc * 2 + 0) * BB + b) * 2048;
    float* p1 = part + ((size_t)(rc * 2 + 1) * BB + b) * 2048;
    ((float2*)p0)[col0 >> 1] = make_float2(a00, a01);
    ((float2*)p1)[col0 >> 1] = make_float2(a10, a11);
  }

  // --- boundary columns n=0 (user) / n=M-1 (item), once per (b, rc) ---
  if (x == 0 && t >= 128 && t < 132) {
    const int idx = t - 128, which = idx & 1, j = idx >> 1;
    const float* __restrict__ src = which ? item : user;
    float acc = 0.f;
#pragma unroll
    for (int i = 0; i < 32; ++i)
      acc += fmaxf(src[b * NROWS + r0 + i], 0.f) * uvs[j][wibase + i];
    bnd[((rc * 2 + j) * BB + b) * 2 + which] = acc;
  }
}

// ---------------------------------------------------------------------------
// Kernel 2: combine partials -> causal weights for target cols {0, M-1}.
//   d_j = s_j·adj[n,mj]·iw[n,mj] − t_j·adj[mj,n]·iw[mj,n]
//   c_j = sigmoid(d_j)·adj[n,mj]   (stable exp(min(d,0)) form)
// ---------------------------------------------------------------------------
__global__ __launch_bounds__(256) void cweight_kernel(
    const float* __restrict__ adj, const float* __restrict__ iw,
    const float* __restrict__ part, const float* __restrict__ bnd,
    float* __restrict__ c) {
  const int idx = blockIdx.x * 256 + threadIdx.x;  // 16*2048
  const int b = idx >> 11, n = idx & (MM - 1);
  float s0, s1, t0v, t1v;
  if (n == 0 || n == MM - 1) {
    const int which = (n == 0) ? 0 : 1;
    s0 = bnd[(0 * BB + b) * 2 + which] + bnd[(2 * BB + b) * 2 + which];
    s1 = bnd[(1 * BB + b) * 2 + which] + bnd[(3 * BB + b) * 2 + which];
    t0v = bnd[(4 * BB + b) * 2 + which] + bnd[(6 * BB + b) * 2 + which];
    t1v = bnd[(5 * BB + b) * 2 + which] + bnd[(7 * BB + b) * 2 + which];
  } else {
    const int col = n - 1;
    s0 = part[((size_t)0 * BB + b) * 2048 + col] +
         part[((size_t)2 * BB + b) * 2048 + col];
    s1 = part[((size_t)1 * BB + b) * 2048 + col] +
         part[((size_t)3 * BB + b) * 2048 + col];
    t0v = part[((size_t)4 * BB + b) * 2048 + col] +
          part[((size_t)6 * BB + b) * 2048 + col];
    t1v = part[((size_t)5 * BB + b) * 2048 + col] +
          part[((size_t)7 * BB + b) * 2048 + col];
  }
  const float an0 = adj[(size_t)n * MM];
  const float an1 = adj[(size_t)n * MM + (MM - 1)];
  const float wn0 = an0 * iw[(size_t)n * MM];
  const float wn1 = an1 * iw[(size_t)n * MM + (MM - 1)];
  const float w0n = adj[n] * iw[n];
  const float w1n =
      adj[(size_t)(MM - 1) * MM + n] * iw[(size_t)(MM - 1) * MM + n];
  const float d0 = s0 * wn0 - t0v * w0n;
  const float d1 = s1 * wn1 - t1v * w1n;
  const float e0 = expf(-fabsf(d0));
  const float e1 = expf(-fabsf(d1));
  const float sig0 = (d0 > 0.f) ? 1.f / (1.f + e0) : e0 / (1.f + e0);
  const float sig1 = (d1 > 0.f) ? 1.f / (1.f + e1) : e1 / (1.f + e1);
  c[b * MM + n] = sig0 * an0;
  c[BB * MM + b * MM + n] = sig1 * an1;
}

// ---------------------------------------------------------------------------
// Kernel 3: g_j[b,r] = sum_n relu(raw[b,128+rv,n])·c_j[b,n].
// Single-wave blocks: pure shuffle reduction, zero barriers, plain store.
// grid (64 rv, 16 b) = 1024 blocks x 64 thr, float2 loads.
// ---------------------------------------------------------------------------
__global__ __launch_bounds__(64) void gather_kernel(
    const float* __restrict__ user, const float* __restrict__ item,
    const float* __restrict__ att, const float* __restrict__ W1,
    const float* __restrict__ c, float* __restrict__ gg) {
  const int rv = blockIdx.x, b = blockIdx.y, t = threadIdx.x;
  const int r = 128 + rv;
  const int gr = b * NROWS + r;
  const float* __restrict__ c0 = c + b * MM;
  const float* __restrict__ c1 = c + BB * MM + b * MM;
  float g0 = 0.f, g1 = 0.f;
#pragma unroll
  for (int i = 0; i < 16; ++i) {
    const int col = i * 128 + 2 * t;
    if (col < AA) {
      const float2 av = ((const float2*)att)[((size_t)gr * AA + col) >> 1];
      const float2 wv = ((const float2*)W1)[((size_t)r * AA + col) >> 1];
      const float v0 = fmaxf(av.x * wv.x, 0.f);
      const float v1 = fmaxf(av.y * wv.y, 0.f);
      g0 += v0 * c0[col + 1] + v1 * c0[col + 2];
      g1 += v0 * c1[col + 1] + v1 * c1[col + 2];
    }
  }
  if (t == 0) {  // boundary cols n=0 (user) / n=M-1 (item)
    const float uval = fmaxf(user[gr], 0.f);
    const float ival = fmaxf(item[gr], 0.f);
    g0 += uval * c0[0] + ival * c0[MM - 1];
    g1 += uval * c1[0] + ival * c1[MM - 1];
  }
#pragma unroll
  for (int o = 32; o > 0; o >>= 1) {
    g0 += __shfl_down(g0, o);
    g1 += __shfl_down(g1, o);
  }
  if (t == 0) ((float2*)gg)[b * 64 + rv] = make_float2(g0, g1);
}

// ---------------------------------------------------------------------------
// Kernel 4: final projection, writes ALL outputs (no memset needed).
//   out[b,l,j] = sum_rv W2[128+rv,l]·g_j[b,rv]
// grid 16 blocks x 64 thr.
// ---------------------------------------------------------------------------
__global__ __launch_bounds__(64) void proj_kernel(
    const float* __restrict__ W2, const float* __restrict__ gg,
    float* __restrict__ out) {
  const int b = blockIdx.x, t = threadIdx.x;
  const int l = t & 31, j = t >> 5;
  float acc = 0.f;
#pragma unroll
  for (int i = 0; i < 64; ++i)
    acc += W2[(128 + i) * LL + l] * gg[(b * 64 + i) * 2 + j];
  out[b * 64 + l * 2 + j] = acc;
}

extern "C" void kernel_launch(void* const* d_in, const int* in_sizes, int n_in,
                              void* d_out, int out_size, void* d_ws,
                              size_t ws_size, hipStream_t stream) {
  const float* user = (const float*)d_in[0];
  const float* item = (const float*)d_in[1];
  const float* att = (const float*)d_in[2];
  const float* adj = (const float*)d_in[3];
  const float* iw = (const float*)d_in[4];
  const float* W1 = (const float*)d_in[5];
  const float* W2 = (const float*)d_in[6];
  float* out = (float*)d_out;

  float* part = (float*)d_ws;          // 4*2*16*2048 = 262144 floats
  float* bnd = part + 262144;          // 4*2*16*2 = 256 floats
  float* c = bnd + 256;                // 2*16*2048 = 65536 floats
  float* gg = c + 65536;               // 16*64*2 = 2048 floats

  stc_kernel<<<dim3(4, BB, 4), 256, 0, stream>>>(user, item, att, W1, W2, part,
                                                 bnd);
  cweight_kernel<<<dim3(BB * MM / 256), 256, 0, stream>>>(adj, iw, part, bnd,
                                                          c);
  gather_kernel<<<dim3(64, BB), 64, 0, stream>>>(user, item, att, W1, c, gg);
  proj_kernel<<<dim3(BB), 64, 0, stream>>>(W2, gg, out);
}

// Round 7
// 115.401 us; speedup vs baseline: 1.8432x; 1.0089x over previous
//
#include <hip/hip_runtime.h>
#include <math.h>

// Problem constants
#define BB 16      // batch
#define LL 32      // L
#define AA 2046    // attributor cols
#define MM 2048    // M = A + 2
#define NROWS 192  // 6L

// Workspace layout (floats):
//   c  [2][16][2048]   causal weights for target cols {0, M-1}
//   gg [16][64][2]     per-value-row reduced sums g_j[b,r]
//
// R5 lesson: NO device-scope fences / last-block patterns (threadfence
// serialized 1024 blocks into 76 µs). Kernel boundaries are the coherence
// mechanism. R6 lesson: grids must cover >=256 blocks or CUs sit idle.

// ---------------------------------------------------------------------------
// Kernel 1 (cfused): embedded prep + FULL per-column s/t + sigmoid -> c.
// One thread owns one column n (grid (16,16) x 128 thr = 2048 cols x 16 b).
//   s_j(n) = sum_{r=0..63}   relu(raw[b,r,n])      * u_j[r]
//   t_j(n) = sum_{r=64..127} relu(raw[b,r,n])      * v_j[r-64]
//   d_j    = s_j*adj[n,mj]*iw[n,mj] - t_j*adj[mj,n]*iw[mj,n]
//   c_j(n) = sigmoid(d_j)*adj[n,mj]      (m0=0, m1=M-1)
// raw[b,r,0]=user, raw[b,r,M-1]=item, else att*W1 — made BRANCHLESS via
// per-thread pointer select (strideW=0 + one cndmask), so the 128-iter loop
// stays a convergent, deeply-pipelined load stream (R3 post-mortem).
// u_j[r]=W2[r,:]·K_j, v_j[r]=W2[64+r,:]·Q_j; K_j/Q_j from user/item rows.
// ---------------------------------------------------------------------------
__global__ __launch_bounds__(128) void cfused_kernel(
    const float* __restrict__ user, const float* __restrict__ item,
    const float* __restrict__ att, const float* __restrict__ W1,
    const float* __restrict__ W2, const float* __restrict__ adj,
    const float* __restrict__ iw, float* __restrict__ c) {
  const int x = blockIdx.x, b = blockIdx.y, t = threadIdx.x;
  __shared__ float KQ[4][LL];   // 0:K0(user) 1:K1(item) 2:Q0(user) 3:Q1(item)
  __shared__ float uvs[4][64];  // 0:u0 1:u1 2:v0 3:v1

  // --- embedded prep (L2-hot user/item/W2) ---
  {
    const int q = t >> 5, l = t & 31;
    const float* __restrict__ src = (q & 1) ? item : user;
    const int rbase = (q < 2) ? 64 : 0;  // K from rows 64..127, Q from 0..63
    float acc = 0.f;
#pragma unroll
    for (int r = 0; r < 64; ++r)
      acc += fmaxf(src[b * NROWS + rbase + r], 0.f) * W2[(rbase + r) * LL + l];
    KQ[q][l] = acc;
  }
  __syncthreads();
#pragma unroll
  for (int k = 0; k < 2; ++k) {
    const int which = (t >> 6) + 2 * k, r = t & 63;
    const int wrow = (which < 2) ? r : 64 + r;
    float acc = 0.f;
#pragma unroll
    for (int l = 0; l < LL; ++l) acc += W2[wrow * LL + l] * KQ[which][l];
    uvs[which][r] = acc;
  }
  __syncthreads();

  // --- per-thread column setup (branchless pointer select) ---
  const int n = x * 128 + t;
  const bool isU = (n == 0), isI = (n == MM - 1), special = isU | isI;
  const float* pA = isU ? (user + b * NROWS)
                        : (isI ? (item + b * NROWS)
                               : (att + (size_t)b * NROWS * AA + (n - 1)));
  const size_t strideA = special ? 1 : AA;
  const float* pW = W1 + (special ? 0 : (n - 1));
  const size_t strideW = special ? 0 : AA;

  // strided c-inputs issued EARLY so their latency hides under the S/T loops
  const float an0 = adj[(size_t)n * MM];
  const float win0 = iw[(size_t)n * MM];
  const float an1 = adj[(size_t)n * MM + (MM - 1)];
  const float win1 = iw[(size_t)n * MM + (MM - 1)];
  const float a0n = adj[n];
  const float i0n = iw[n];
  const float a1n = adj[(size_t)(MM - 1) * MM + n];
  const float i1n = iw[(size_t)(MM - 1) * MM + n];

  float s0 = 0.f, s1 = 0.f, t0 = 0.f, t1 = 0.f;
#pragma unroll 16
  for (int r = 0; r < 64; ++r) {
    const float a = pA[(size_t)r * strideA];
    const float w = pW[(size_t)r * strideW];
    const float v = fmaxf(special ? a : a * w, 0.f);
    s0 += v * uvs[0][r];
    s1 += v * uvs[1][r];
  }
#pragma unroll 16
  for (int r = 64; r < 128; ++r) {
    const float a = pA[(size_t)r * strideA];
    const float w = pW[(size_t)r * strideW];
    const float v = fmaxf(special ? a : a * w, 0.f);
    t0 += v * uvs[2][r - 64];
    t1 += v * uvs[3][r - 64];
  }

  const float wn0 = an0 * win0, wn1 = an1 * win1;
  const float w0n = a0n * i0n, w1n = a1n * i1n;
  const float d0 = s0 * wn0 - t0 * w0n;
  const float d1 = s1 * wn1 - t1 * w1n;
  // stable sigmoid == exp(min(d,0)) / (exp(min(d,0)) + exp(min(-d,0)))
  const float e0 = expf(-fabsf(d0));
  const float e1 = expf(-fabsf(d1));
  const float sig0 = (d0 > 0.f) ? 1.f / (1.f + e0) : e0 / (1.f + e0);
  const float sig1 = (d1 > 0.f) ? 1.f / (1.f + e1) : e1 / (1.f + e1);
  c[b * MM + n] = sig0 * an0;
  c[BB * MM + b * MM + n] = sig1 * an1;
}

// ---------------------------------------------------------------------------
// Kernel 2: g_j[b,r] = sum_n relu(raw[b,128+rv,n])·c_j[b,n].
// Single-wave blocks: pure shuffle reduction, zero barriers, plain store.
// grid (64 rv, 16 b) = 1024 blocks x 64 thr, float2 loads.
// ---------------------------------------------------------------------------
__global__ __launch_bounds__(64) void gather_kernel(
    const float* __restrict__ user, const float* __restrict__ item,
    const float* __restrict__ att, const float* __restrict__ W1,
    const float* __restrict__ c, float* __restrict__ gg) {
  const int rv = blockIdx.x, b = blockIdx.y, t = threadIdx.x;
  const int r = 128 + rv;
  const int gr = b * NROWS + r;
  const float* __restrict__ c0 = c + b * MM;
  const float* __restrict__ c1 = c + BB * MM + b * MM;
  float g0 = 0.f, g1 = 0.f;
#pragma unroll
  for (int i = 0; i < 16; ++i) {
    const int col = i * 128 + 2 * t;
    if (col < AA) {
      const float2 av = ((const float2*)att)[((size_t)gr * AA + col) >> 1];
      const float2 wv = ((const float2*)W1)[((size_t)r * AA + col) >> 1];
      const float v0 = fmaxf(av.x * wv.x, 0.f);
      const float v1 = fmaxf(av.y * wv.y, 0.f);
      g0 += v0 * c0[col + 1] + v1 * c0[col + 2];
      g1 += v0 * c1[col + 1] + v1 * c1[col + 2];
    }
  }
  if (t == 0) {  // boundary cols n=0 (user) / n=M-1 (item)
    const float uval = fmaxf(user[gr], 0.f);
    const float ival = fmaxf(item[gr], 0.f);
    g0 += uval * c0[0] + ival * c0[MM - 1];
    g1 += uval * c1[0] + ival * c1[MM - 1];
  }
#pragma unroll
  for (int o = 32; o > 0; o >>= 1) {
    g0 += __shfl_down(g0, o);
    g1 += __shfl_down(g1, o);
  }
  if (t == 0) ((float2*)gg)[b * 64 + rv] = make_float2(g0, g1);
}

// ---------------------------------------------------------------------------
// Kernel 3: final projection, writes ALL outputs (no memset needed).
//   out[b,l,j] = sum_rv W2[128+rv,l]·g_j[b,rv]
// grid 16 blocks x 64 thr.
// ---------------------------------------------------------------------------
__global__ __launch_bounds__(64) void proj_kernel(
    const float* __restrict__ W2, const float* __restrict__ gg,
    float* __restrict__ out) {
  const int b = blockIdx.x, t = threadIdx.x;
  const int l = t & 31, j = t >> 5;
  float acc = 0.f;
#pragma unroll
  for (int i = 0; i < 64; ++i)
    acc += W2[(128 + i) * LL + l] * gg[(b * 64 + i) * 2 + j];
  out[b * 64 + l * 2 + j] = acc;
}

extern "C" void kernel_launch(void* const* d_in, const int* in_sizes, int n_in,
                              void* d_out, int out_size, void* d_ws,
                              size_t ws_size, hipStream_t stream) {
  const float* user = (const float*)d_in[0];
  const float* item = (const float*)d_in[1];
  const float* att = (const float*)d_in[2];
  const float* adj = (const float*)d_in[3];
  const float* iw = (const float*)d_in[4];
  const float* W1 = (const float*)d_in[5];
  const float* W2 = (const float*)d_in[6];
  float* out = (float*)d_out;

  float* c = (float*)d_ws;        // 2*16*2048 = 65536 floats
  float* gg = c + 2 * BB * MM;    // 16*64*2 = 2048 floats

  cfused_kernel<<<dim3(16, BB), 128, 0, stream>>>(user, item, att, W1, W2, adj,
                                                  iw, c);
  gather_kernel<<<dim3(64, BB), 64, 0, stream>>>(user, item, att, W1, c, gg);
  proj_kernel<<<dim3(BB), 64, 0, stream>>>(W2, gg, out);
}

// Round 8
// 113.755 us; speedup vs baseline: 1.8699x; 1.0145x over previous
//
#include <hip/hip_runtime.h>
#include <math.h>

// Problem constants
#define BB 16      // batch
#define LL 32      // L
#define AA 2046    // attributor cols
#define MM 2048    // M = A + 2
#define NROWS 192  // 6L

// Workspace layout (floats):
//   uv  [4][16][64]       u0,u1,v0,v1 weights (4096)
//   bnd [2][2][2][16]     boundary s/t sums: [j][s|t][user|item][b] (128)
//   part[16][16][2048]    8 rc-chunks x 2 j of s/t partials (524288)
//   c   [2][16][2048]     causal weights for target cols {0, M-1} (65536)
//   gg  [16][64][2]       per-value-row reduced sums g_j[b,r] (2048)
//
// Session lessons: R5 — NO device-scope fences (L2 writeback per fence
// serialized 1024 blocks into 76 us). R7 vs R4 — wave count is the lever;
// keep >=2048 waves in the big kernels, don't trade blocks for vector width.

// ---------------------------------------------------------------------------
// Kernel 0: per-batch prep (16 blocks x 256).
//   K_j[l] = sum_{r=64..127} relu(src_j[b,r]) W2[r,l]   (src_0=user, 1=item)
//   Q_j[l] = sum_{r=0..63}   relu(src_j[b,r]) W2[r,l]
//   u_j[r] = W2[r,:]·K_j  (r<64, weights for s_j)
//   v_j[r] = W2[64+r,:]·Q_j            (weights for t_j)
//   bnd: full boundary-column sums  s_j/t_j for n=0 (user) and n=M-1 (item).
// ---------------------------------------------------------------------------
__global__ __launch_bounds__(256) void prep_kernel(
    const float* __restrict__ user, const float* __restrict__ item,
    const float* __restrict__ W2, float* __restrict__ uv,
    float* __restrict__ bnd) {
  const int b = blockIdx.x, t = threadIdx.x;
  __shared__ float KQ[4][LL];   // 0:K0(user) 1:K1(item) 2:Q0(user) 3:Q1(item)
  __shared__ float uvs[4][64];  // 0:u0 1:u1 2:v0 3:v1
  if (t < 128) {
    const int q = t >> 5, l = t & 31;
    const float* __restrict__ src = (q & 1) ? item : user;
    const int rbase = (q < 2) ? 64 : 0;  // K from rows 64..127, Q from 0..63
    float acc = 0.f;
#pragma unroll
    for (int r = 0; r < 64; ++r)
      acc += fmaxf(src[b * NROWS + rbase + r], 0.f) * W2[(rbase + r) * LL + l];
    KQ[q][l] = acc;
  }
  __syncthreads();
  {
    const int which = t >> 6, r = t & 63;
    const int wrow = (which < 2) ? r : 64 + r;
    float acc = 0.f;
#pragma unroll
    for (int l = 0; l < LL; ++l) acc += W2[wrow * LL + l] * KQ[which][l];
    uvs[which][r] = acc;
    uv[which * (BB * 64) + b * 64 + r] = acc;
  }
  __syncthreads();
  if (t < 8) {
    const int which = t & 1, j = (t >> 1) & 1, stv = t >> 2;
    const float* __restrict__ src = which ? item : user;
    float acc = 0.f;
    if (stv == 0) {
#pragma unroll
      for (int r = 0; r < 64; ++r)
        acc += fmaxf(src[b * NROWS + r], 0.f) * uvs[j][r];
    } else {
#pragma unroll
      for (int r = 0; r < 64; ++r)
        acc += fmaxf(src[b * NROWS + 64 + r], 0.f) * uvs[2 + j][r];
    }
    bnd[((j * 2 + stv) * 2 + which) * BB + b] = acc;
  }
}

// ---------------------------------------------------------------------------
// Kernel 1: s/t partials over interior columns. 8 r-chunks of 16 rows keep
// 512 blocks x 4 waves alive WITH float2 loads (R4 parallelism + R6 widths).
//   rc 0..3 (z=0): s-partials, weights u0/u1;  rc 4..7 (z=1): t, v0/v1.
// grid (4 coltiles, 16 b, 8 rc) = 512 blocks x 256 thr, 2 cols/thread.
// uv read directly from global (wave-uniform -> scalar loads, L2-hot).
// ---------------------------------------------------------------------------
__global__ __launch_bounds__(256) void st_kernel(
    const float* __restrict__ att, const float* __restrict__ W1,
    const float* __restrict__ uv, float* __restrict__ part) {
  const int x = blockIdx.x, b = blockIdx.y, rc = blockIdx.z;
  const int t = threadIdx.x;
  const int z = rc >> 2;
  const int col0 = x * 512 + 2 * t;
  if (col0 >= AA) return;
  const float* __restrict__ w0 = uv + (2 * z) * (BB * 64) + b * 64;
  const float* __restrict__ w1 = uv + (2 * z + 1) * (BB * 64) + b * 64;
  const int r0 = rc * 16;
  const int wibase = r0 - z * 64;
  float a00 = 0.f, a01 = 0.f, a10 = 0.f, a11 = 0.f;
#pragma unroll
  for (int i = 0; i < 16; ++i) {
    const int r = r0 + i;
    const float2 av =
        ((const float2*)att)[((size_t)(b * NROWS + r) * AA + col0) >> 1];
    const float2 wv = ((const float2*)W1)[((size_t)r * AA + col0) >> 1];
    const float v0 = fmaxf(av.x * wv.x, 0.f);
    const float v1 = fmaxf(av.y * wv.y, 0.f);
    const float u0 = w0[wibase + i], u1 = w1[wibase + i];
    a00 += v0 * u0;
    a01 += v1 * u0;
    a10 += v0 * u1;
    a11 += v1 * u1;
  }
  float* p0 = part + ((size_t)(rc * 2 + 0) * BB + b) * 2048;
  float* p1 = part + ((size_t)(rc * 2 + 1) * BB + b) * 2048;
  ((float2*)p0)[col0 >> 1] = make_float2(a00, a01);
  ((float2*)p1)[col0 >> 1] = make_float2(a10, a11);
}

// ---------------------------------------------------------------------------
// Kernel 2: combine partials -> causal weights for target cols {0, M-1}.
//   d_j = s_j·adj[n,mj]·iw[n,mj] − t_j·adj[mj,n]·iw[mj,n]
//   c_j = sigmoid(d_j)·adj[n,mj]     (stable exp(min(d,0)) form)
// grid 128 blocks x 256 thr, coalesced over n.
// ---------------------------------------------------------------------------
__global__ __launch_bounds__(256) void cweight_kernel(
    const float* __restrict__ adj, const float* __restrict__ iw,
    const float* __restrict__ part, const float* __restrict__ bnd,
    float* __restrict__ c) {
  const int idx = blockIdx.x * 256 + threadIdx.x;  // 16*2048
  const int b = idx >> 11, n = idx & (MM - 1);
  float s0, s1, t0v, t1v;
  if (n == 0 || n == MM - 1) {
    const int which = (n == 0) ? 0 : 1;
    s0 = bnd[((0 * 2 + 0) * 2 + which) * BB + b];
    s1 = bnd[((1 * 2 + 0) * 2 + which) * BB + b];
    t0v = bnd[((0 * 2 + 1) * 2 + which) * BB + b];
    t1v = bnd[((1 * 2 + 1) * 2 + which) * BB + b];
  } else {
    const int col = n - 1;
    s0 = s1 = t0v = t1v = 0.f;
#pragma unroll
    for (int rc = 0; rc < 4; ++rc) {
      s0 += part[((size_t)(rc * 2 + 0) * BB + b) * 2048 + col];
      s1 += part[((size_t)(rc * 2 + 1) * BB + b) * 2048 + col];
      t0v += part[((size_t)((rc + 4) * 2 + 0) * BB + b) * 2048 + col];
      t1v += part[((size_t)((rc + 4) * 2 + 1) * BB + b) * 2048 + col];
    }
  }
  const float an0 = adj[(size_t)n * MM];
  const float an1 = adj[(size_t)n * MM + (MM - 1)];
  const float wn0 = an0 * iw[(size_t)n * MM];
  const float wn1 = an1 * iw[(size_t)n * MM + (MM - 1)];
  const float w0n = adj[n] * iw[n];
  const float w1n =
      adj[(size_t)(MM - 1) * MM + n] * iw[(size_t)(MM - 1) * MM + n];
  const float d0 = s0 * wn0 - t0v * w0n;
  const float d1 = s1 * wn1 - t1v * w1n;
  const float e0 = expf(-fabsf(d0));
  const float e1 = expf(-fabsf(d1));
  const float sig0 = (d0 > 0.f) ? 1.f / (1.f + e0) : e0 / (1.f + e0);
  const float sig1 = (d1 > 0.f) ? 1.f / (1.f + e1) : e1 / (1.f + e1);
  c[b * MM + n] = sig0 * an0;
  c[BB * MM + b * MM + n] = sig1 * an1;
}

// ---------------------------------------------------------------------------
// Kernel 3: g_j[b,r] = sum_n relu(raw[b,128+rv,n])·c_j[b,n].
// 256-thr blocks (4096 waves total — R4's winning parallelism), float2 loads,
// wave-shuffle reduce + single LDS step, plain float2 store of g.
// grid (64 rv, 16 b) = 1024 blocks x 256 thr.
// ---------------------------------------------------------------------------
__global__ __launch_bounds__(256) void gather_kernel(
    const float* __restrict__ user, const float* __restrict__ item,
    const float* __restrict__ att, const float* __restrict__ W1,
    const float* __restrict__ c, float* __restrict__ gg) {
  const int rv = blockIdx.x, b = blockIdx.y, t = threadIdx.x;
  const int r = 128 + rv;
  const int gr = b * NROWS + r;
  const float* __restrict__ c0 = c + b * MM;
  const float* __restrict__ c1 = c + BB * MM + b * MM;
  float g0 = 0.f, g1 = 0.f;
#pragma unroll
  for (int i = 0; i < 4; ++i) {
    const int col = i * 512 + 2 * t;
    if (col < AA) {
      const float2 av = ((const float2*)att)[((size_t)gr * AA + col) >> 1];
      const float2 wv = ((const float2*)W1)[((size_t)r * AA + col) >> 1];
      const float v0 = fmaxf(av.x * wv.x, 0.f);
      const float v1 = fmaxf(av.y * wv.y, 0.f);
      g0 += v0 * c0[col + 1] + v1 * c0[col + 2];
      g1 += v0 * c1[col + 1] + v1 * c1[col + 2];
    }
  }
  if (t == 0) {  // boundary cols n=0 (user) / n=M-1 (item)
    const float uval = fmaxf(user[gr], 0.f);
    const float ival = fmaxf(item[gr], 0.f);
    g0 += uval * c0[0] + ival * c0[MM - 1];
    g1 += uval * c1[0] + ival * c1[MM - 1];
  }
#pragma unroll
  for (int o = 32; o > 0; o >>= 1) {
    g0 += __shfl_down(g0, o);
    g1 += __shfl_down(g1, o);
  }
  __shared__ float rg[2][4];
  if ((t & 63) == 0) {
    rg[0][t >> 6] = g0;
    rg[1][t >> 6] = g1;
  }
  __syncthreads();
  if (t == 0) {
    const float s0 = rg[0][0] + rg[0][1] + rg[0][2] + rg[0][3];
    const float s1 = rg[1][0] + rg[1][1] + rg[1][2] + rg[1][3];
    ((float2*)gg)[b * 64 + rv] = make_float2(s0, s1);
  }
}

// ---------------------------------------------------------------------------
// Kernel 4: final projection, writes ALL outputs (no memset needed).
//   out[b,l,j] = sum_rv W2[128+rv,l]·g_j[b,rv]
// grid 16 blocks x 64 thr.
// ---------------------------------------------------------------------------
__global__ __launch_bounds__(64) void proj_kernel(
    const float* __restrict__ W2, const float* __restrict__ gg,
    float* __restrict__ out) {
  const int b = blockIdx.x, t = threadIdx.x;
  const int l = t & 31, j = t >> 5;
  float acc = 0.f;
#pragma unroll
  for (int i = 0; i < 64; ++i)
    acc += W2[(128 + i) * LL + l] * gg[(b * 64 + i) * 2 + j];
  out[b * 64 + l * 2 + j] = acc;
}

extern "C" void kernel_launch(void* const* d_in, const int* in_sizes, int n_in,
                              void* d_out, int out_size, void* d_ws,
                              size_t ws_size, hipStream_t stream) {
  const float* user = (const float*)d_in[0];
  const float* item = (const float*)d_in[1];
  const float* att = (const float*)d_in[2];
  const float* adj = (const float*)d_in[3];
  const float* iw = (const float*)d_in[4];
  const float* W1 = (const float*)d_in[5];
  const float* W2 = (const float*)d_in[6];
  float* out = (float*)d_out;

  float* uv = (float*)d_ws;        // 4*16*64 = 4096 floats
  float* bnd = uv + 4 * BB * 64;   // 128 floats
  float* part = bnd + 128;         // 16*16*2048 = 524288 floats
  float* c = part + 524288;        // 2*16*2048 = 65536 floats
  float* gg = c + 2 * BB * MM;     // 2048 floats

  prep_kernel<<<dim3(BB), 256, 0, stream>>>(user, item, W2, uv, bnd);
  st_kernel<<<dim3(4, BB, 8), 256, 0, stream>>>(att, W1, uv, part);
  cweight_kernel<<<dim3(BB * MM / 256), 256, 0, stream>>>(adj, iw, part, bnd,
                                                          c);
  gather_kernel<<<dim3(64, BB), 256, 0, stream>>>(user, item, att, W1, c, gg);
  proj_kernel<<<dim3(BB), 64, 0, stream>>>(W2, gg, out);
}